// Round 1
// baseline (9717.738 us; speedup 1.0000x reference)
//
#include <hip/hip_runtime.h>

// Neural SDE Euler-Maruyama rollout.
// B=1024 independent trajectories -> each block owns R=8 rows for the whole
// T=127-step rollout. Single kernel launch, no cross-block dependency.

#define Bb   1024
#define Nn   64
#define Cc   16
#define Mm   16
#define Hh   512
#define Tt   128
#define Dd   80            // N + C
#define R    8             // rows per block
#define NT   512           // threads per block (8 waves)

__global__ __launch_bounds__(NT) void nsde_rollout(
    const float* __restrict__ y0,
    const float* __restrict__ controls,
    const float* __restrict__ noise,
    const float* __restrict__ W1_mu, const float* __restrict__ b1_mu,
    const float* __restrict__ W2_mu, const float* __restrict__ b2_mu,
    const float* __restrict__ W1_sg, const float* __restrict__ b1_sg,
    const float* __restrict__ W2_sg, const float* __restrict__ b2_sg,
    float* __restrict__ out)
{
    const int tid = threadIdx.x;
    const int r0  = blockIdx.x * R;

    __shared__ float s_y[R][Nn];          // 2 KB
    __shared__ float s_x[R][Dd];          // 2.5 KB
    __shared__ float s_h[R][Hh];          // 16 KB (reused mu -> sg)
    __shared__ float s_part[R][Nn * Mm];  // 32 KB  (diff * dW partials)
    __shared__ float s_dw[R][Mm];         // 0.5 KB

    // init y from y0; write trajectory slab 0 (= y0, exact)
    for (int idx = tid; idx < R * Nn; idx += NT) {
        int r = idx / Nn, n = idx % Nn;
        float v = y0[(r0 + r) * Nn + n];
        s_y[r][n] = v;
        out[(size_t)(r0 + r) * Nn + n] = v;
    }
    __syncthreads();

    const float sqrt_dt = 0.1f;   // sqrt(0.01)
    const float dt      = 0.01f;

    const int rr = tid / Nn;      // 0..7  (wave-uniform: one wave per row)
    const int nn = tid % Nn;      // 0..63

    for (int k = 0; k < Tt - 1; ++k) {
        // ---- build x = [y, u_k] and dW = z * sqrt(dt)
        for (int idx = tid; idx < R * Dd; idx += NT) {
            int r = idx / Dd, i = idx % Dd;
            s_x[r][i] = (i < Nn) ? s_y[r][i] : controls[k * Cc + (i - Nn)];
        }
        if (tid < R * Mm) {
            int r = tid / Mm, m = tid % Mm;
            s_dw[r][m] = noise[((size_t)k * Bb + (r0 + r)) * Mm + m] * sqrt_dt;
        }
        __syncthreads();

        // ---- mu layer1: h = relu(x @ W1_mu + b1), thread j = tid over H
        {
            float acc[R];
            float bj = b1_mu[tid];
            #pragma unroll
            for (int r = 0; r < R; ++r) acc[r] = bj;
            #pragma unroll 4
            for (int i = 0; i < Dd; ++i) {
                float w = W1_mu[i * Hh + tid];
                #pragma unroll
                for (int r = 0; r < R; ++r) acc[r] += s_x[r][i] * w;
            }
            #pragma unroll
            for (int r = 0; r < R; ++r) s_h[r][tid] = fmaxf(acc[r], 0.0f);
        }
        __syncthreads();

        // ---- drift = h @ W2_mu + b2_mu   (thread -> (rr, nn), kept in reg)
        float drift = b2_mu[nn];
        #pragma unroll 4
        for (int kk = 0; kk < Hh; ++kk) {
            drift += s_h[rr][kk] * W2_mu[kk * Nn + nn];
        }
        __syncthreads();   // all reads of s_h (mu) done before overwrite

        // ---- sg layer1: h = relu(x @ W1_sg + b1)
        {
            float acc[R];
            float bj = b1_sg[tid];
            #pragma unroll
            for (int r = 0; r < R; ++r) acc[r] = bj;
            #pragma unroll 4
            for (int i = 0; i < Dd; ++i) {
                float w = W1_sg[i * Hh + tid];
                #pragma unroll
                for (int r = 0; r < R; ++r) acc[r] += s_x[r][i] * w;
            }
            #pragma unroll
            for (int r = 0; r < R; ++r) s_h[r][tid] = fmaxf(acc[r], 0.0f);
        }
        __syncthreads();

        // ---- diff columns: thread owns cols {tid, tid+512}, all 8 rows.
        // Each weight W2_sg[kk][c] loaded exactly once per block (no replication).
        #pragma unroll
        for (int half = 0; half < 2; ++half) {
            const int c = tid + half * NT;
            float acc[R];
            #pragma unroll
            for (int r = 0; r < R; ++r) acc[r] = 0.f;
            #pragma unroll 4
            for (int kk = 0; kk < Hh; ++kk) {
                float w = W2_sg[kk * (Nn * Mm) + c];
                #pragma unroll
                for (int r = 0; r < R; ++r) acc[r] += s_h[r][kk] * w;
            }
            const float b = b2_sg[c];
            const int m = c & (Mm - 1);
            #pragma unroll
            for (int r = 0; r < R; ++r)
                s_part[r][c] = (acc[r] + b) * s_dw[r][m];
        }
        __syncthreads();

        // ---- y update: y += drift*dt + sum_m diff[n][m]*dW[m]
        {
            float delta = drift * dt;
            #pragma unroll
            for (int m = 0; m < Mm; ++m)
                delta += s_part[rr][nn * Mm + m];
            float ynew = s_y[rr][nn] + delta;
            s_y[rr][nn] = ynew;   // bijective tid <-> (rr,nn): no race
            out[((size_t)(k + 1) * Bb + (r0 + rr)) * Nn + nn] = ynew;
        }
        __syncthreads();   // y complete before next x-build
    }
}

extern "C" void kernel_launch(void* const* d_in, const int* in_sizes, int n_in,
                              void* d_out, int out_size, void* d_ws, size_t ws_size,
                              hipStream_t stream) {
    const float* y0       = (const float*)d_in[0];
    const float* controls = (const float*)d_in[1];
    const float* noise    = (const float*)d_in[2];
    const float* W1_mu    = (const float*)d_in[3];
    const float* b1_mu    = (const float*)d_in[4];
    const float* W2_mu    = (const float*)d_in[5];
    const float* b2_mu    = (const float*)d_in[6];
    const float* W1_sg    = (const float*)d_in[7];
    const float* b1_sg    = (const float*)d_in[8];
    const float* W2_sg    = (const float*)d_in[9];
    const float* b2_sg    = (const float*)d_in[10];
    float* out = (float*)d_out;

    dim3 grid(Bb / R);   // 128 blocks
    dim3 block(NT);      // 512 threads
    nsde_rollout<<<grid, block, 0, stream>>>(
        y0, controls, noise,
        W1_mu, b1_mu, W2_mu, b2_mu,
        W1_sg, b1_sg, W2_sg, b2_sg,
        out);
}

// Round 2
// 7935.056 us; speedup vs baseline: 1.2247x; 1.2247x over previous
//
#include <hip/hip_runtime.h>

// Neural SDE rollout via fp16x2 split-precision MFMA (16x16x32_f16).
// Each value v = hi + lo (two fp16); products hi*hi + hi*lo + lo*hi in 3
// MFMAs with fp32 accumulation => ~2^-22 relative truncation, below the
// fp32 reassociation noise floor (R1 absmax 2.0 vs threshold 18.88).
//
// Weights are split+shuffled ONCE per launch into exact MFMA B-fragment
// order in d_ws (2.6 MB, L2-resident), so every inner-loop B-load is one
// coalesced global_load_dwordx4 per lane.

typedef _Float16 f16x8 __attribute__((ext_vector_type(8)));
typedef float    f32x4 __attribute__((ext_vector_type(4)));

#define MFMA(a,b,c) __builtin_amdgcn_mfma_f32_16x16x32_f16(a,b,c,0,0,0)

#define Bb 1024
#define Nn 64
#define Cc 16
#define Mm 16
#define Hh 512
#define Tt 128
#define R  16     // batch rows per block -> 64 blocks
#define NT 512    // 8 waves

// packed fragment regions in d_ws (units: halves)
// slot(tile,ks,p) = ((tile*KSTEPS + ks)*2 + p)*512, lane offset = lane*8
#define W2SG_OFF 0
#define W2SG_HALVES (64*16*2*512)
#define W2MU_OFF (W2SG_OFF + W2SG_HALVES)
#define W2MU_HALVES (4*16*2*512)
#define W1MU_OFF (W2MU_OFF + W2MU_HALVES)
#define W1_HALVES (32*3*2*512)
#define W1SG_OFF (W1MU_OFF + W1_HALVES)

__global__ __launch_bounds__(256) void pack_weights(
    const float* __restrict__ W1_mu, const float* __restrict__ W2_mu,
    const float* __restrict__ W1_sg, const float* __restrict__ W2_sg,
    _Float16* __restrict__ wsh)
{
    int gid = blockIdx.x * 256 + threadIdx.x;
    if (gid >= 81920) return;
    const float* src; int ncols, kvalid; size_t dst;
    int id, tile, ks, lane;
    if (gid < 65536) {                 // W2_sg: 64 tiles x 16 ks x 64 lanes
        id = gid; tile = id >> 10; id &= 1023; ks = id >> 6; lane = id & 63;
        src = W2_sg; ncols = 1024; kvalid = 512;
        dst = W2SG_OFF + (size_t)((tile*16 + ks)*2) * 512 + lane*8;
    } else if (gid < 69632) {          // W2_mu: 4 x 16 x 64
        id = gid - 65536; tile = id >> 10; id &= 1023; ks = id >> 6; lane = id & 63;
        src = W2_mu; ncols = 64; kvalid = 512;
        dst = W2MU_OFF + (size_t)((tile*16 + ks)*2) * 512 + lane*8;
    } else if (gid < 75776) {          // W1_mu: 32 tiles x 3 ks x 64
        id = gid - 69632; tile = id / 192; id %= 192; ks = id >> 6; lane = id & 63;
        src = W1_mu; ncols = 512; kvalid = 80;
        dst = W1MU_OFF + (size_t)((tile*3 + ks)*2) * 512 + lane*8;
    } else {                           // W1_sg
        id = gid - 75776; tile = id / 192; id %= 192; ks = id >> 6; lane = id & 63;
        src = W1_sg; ncols = 512; kvalid = 80;
        dst = W1SG_OFF + (size_t)((tile*3 + ks)*2) * 512 + lane*8;
    }
    const int n  = tile*16 + (lane & 15);
    const int kb = ks*32 + ((lane >> 4) << 3);
    f16x8 hi8, lo8;
    #pragma unroll
    for (int j = 0; j < 8; ++j) {
        int k = kb + j;
        float wv = (k < kvalid) ? src[(size_t)k * ncols + n] : 0.f;
        _Float16 h = (_Float16)wv;
        hi8[j] = h;
        lo8[j] = (_Float16)(wv - (float)h);
    }
    *((f16x8*)(wsh + dst))       = hi8;
    *((f16x8*)(wsh + dst + 512)) = lo8;
}

__global__ __launch_bounds__(NT) void nsde_mfma(
    const float* __restrict__ y0, const float* __restrict__ controls,
    const float* __restrict__ noise,
    const float* __restrict__ b1_mu, const float* __restrict__ b2_mu,
    const float* __restrict__ b1_sg, const float* __restrict__ b2_sg,
    const _Float16* __restrict__ wf,
    float* __restrict__ out)
{
    __shared__ _Float16 s_xhi[R][104], s_xlo[R][104];   // x padded K=96 (+8 pad)
    __shared__ _Float16 s_hhi[R][520], s_hlo[R][520];   // h (reused mu->sg)
    __shared__ float s_y[R][Nn], s_dw[R][Mm], s_delta[R][Nn], s_drift[R][Nn];

    const int tid  = threadIdx.x;
    const int lane = tid & 63, w = tid >> 6;
    const int m15  = lane & 15, quad = lane >> 4;
    const int r0   = blockIdx.x * R;

    // ---- init: y0 -> s_y, out slab 0, x split; controls0; pad; dW0
    for (int e = tid; e < R*Nn; e += NT) {
        int r = e >> 6, n = e & 63;
        float v = y0[(size_t)(r0+r)*Nn + n];
        s_y[r][n] = v;
        out[(size_t)(r0+r)*Nn + n] = v;
        _Float16 h = (_Float16)v;
        s_xhi[r][n] = h; s_xlo[r][n] = (_Float16)(v - (float)h);
    }
    if (tid < Cc) {
        float u = controls[tid];
        _Float16 h = (_Float16)u, l = (_Float16)(u - (float)h);
        for (int r = 0; r < R; ++r) { s_xhi[r][64+tid] = h; s_xlo[r][64+tid] = l; }
    }
    if (tid < 256) {
        int r = tid >> 4, c = tid & 15;
        s_xhi[r][80+c] = (_Float16)0.f; s_xlo[r][80+c] = (_Float16)0.f;   // K pad
        s_dw[r][c] = noise[(size_t)(r0+r)*Mm + c] * 0.1f;
    }
    __syncthreads();

    // GEMM1: h = relu(x @ W1 + b1); 32 H-tiles over 8 waves (2 pairs each)
    auto gemm1 = [&](const _Float16* wbase, const float* bias) {
        const int tbase = w * 4;
        for (int tp = 0; tp < 2; ++tp) {
            const int ta = tbase + tp*2, tb = ta + 1;
            f32x4 hh0 = {0,0,0,0}, hl0 = {0,0,0,0}, lh0 = {0,0,0,0};
            f32x4 hh1 = {0,0,0,0}, hl1 = {0,0,0,0}, lh1 = {0,0,0,0};
            #pragma unroll
            for (int ks = 0; ks < 3; ++ks) {
                f16x8 ah = *(const f16x8*)&s_xhi[m15][quad*8 + ks*32];
                f16x8 al = *(const f16x8*)&s_xlo[m15][quad*8 + ks*32];
                f16x8 bha = *((const f16x8*)(wbase + (size_t)((ta*3+ks)*2+0)*512) + lane);
                f16x8 bla = *((const f16x8*)(wbase + (size_t)((ta*3+ks)*2+1)*512) + lane);
                f16x8 bhb = *((const f16x8*)(wbase + (size_t)((tb*3+ks)*2+0)*512) + lane);
                f16x8 blb = *((const f16x8*)(wbase + (size_t)((tb*3+ks)*2+1)*512) + lane);
                hh0 = MFMA(ah, bha, hh0); hl0 = MFMA(ah, bla, hl0); lh0 = MFMA(al, bha, lh0);
                hh1 = MFMA(ah, bhb, hh1); hl1 = MFMA(ah, blb, hl1); lh1 = MFMA(al, bhb, lh1);
            }
            f32x4 a0 = hh0 + hl0 + lh0, a1 = hh1 + hl1 + lh1;
            const int ca = ta*16 + m15, cb = tb*16 + m15;
            const float ba = bias[ca], bbv = bias[cb];
            #pragma unroll
            for (int rg = 0; rg < 4; ++rg) {
                const int row = quad*4 + rg;
                float va = fmaxf(a0[rg] + ba, 0.f);
                _Float16 h1 = (_Float16)va;
                s_hhi[row][ca] = h1; s_hlo[row][ca] = (_Float16)(va - (float)h1);
                float vb = fmaxf(a1[rg] + bbv, 0.f);
                _Float16 h2 = (_Float16)vb;
                s_hhi[row][cb] = h2; s_hlo[row][cb] = (_Float16)(vb - (float)h2);
            }
        }
    };

    for (int k = 0; k < Tt-1; ++k) {
        // ---- phase 1: h_mu
        gemm1(wf + W1MU_OFF, b1_mu);
        __syncthreads();

        // ---- phase 2: drift = h_mu @ W2_mu + b2_mu (waves 0..3)
        if (w < 4) {
            const _Float16* base = wf + W2MU_OFF;
            const int t = w;
            f32x4 hh = {0,0,0,0}, hl = {0,0,0,0}, lh = {0,0,0,0};
            #pragma unroll
            for (int ks = 0; ks < 16; ++ks) {
                f16x8 ah = *(const f16x8*)&s_hhi[m15][quad*8 + ks*32];
                f16x8 al = *(const f16x8*)&s_hlo[m15][quad*8 + ks*32];
                f16x8 bh = *((const f16x8*)(base + (size_t)((t*16+ks)*2+0)*512) + lane);
                f16x8 bl = *((const f16x8*)(base + (size_t)((t*16+ks)*2+1)*512) + lane);
                hh = MFMA(ah, bh, hh); hl = MFMA(ah, bl, hl); lh = MFMA(al, bh, lh);
            }
            f32x4 a = hh + hl + lh;
            const int c = t*16 + m15;
            const float b2 = b2_mu[c];
            #pragma unroll
            for (int rg = 0; rg < 4; ++rg) s_drift[quad*4+rg][c] = a[rg] + b2;
        }
        __syncthreads();

        // ---- phase 3: h_sg (overwrites h buffer)
        gemm1(wf + W1SG_OFF, b1_sg);
        __syncthreads();

        // ---- phase 4: diff = h_sg @ W2_sg + b2_sg, fused m-contraction with dW
        {
            float dwv[4];
            #pragma unroll
            for (int rg = 0; rg < 4; ++rg) dwv[rg] = s_dw[quad*4+rg][m15];
            const _Float16* base = wf + W2SG_OFF;
            for (int tp = 0; tp < 4; ++tp) {
                const int ta = w*8 + tp*2, tb = ta + 1;
                f32x4 hh0 = {0,0,0,0}, hl0 = {0,0,0,0}, lh0 = {0,0,0,0};
                f32x4 hh1 = {0,0,0,0}, hl1 = {0,0,0,0}, lh1 = {0,0,0,0};
                #pragma unroll
                for (int ks = 0; ks < 16; ++ks) {
                    f16x8 ah = *(const f16x8*)&s_hhi[m15][quad*8 + ks*32];
                    f16x8 al = *(const f16x8*)&s_hlo[m15][quad*8 + ks*32];
                    f16x8 bha = *((const f16x8*)(base + (size_t)((ta*16+ks)*2+0)*512) + lane);
                    f16x8 bla = *((const f16x8*)(base + (size_t)((ta*16+ks)*2+1)*512) + lane);
                    f16x8 bhb = *((const f16x8*)(base + (size_t)((tb*16+ks)*2+0)*512) + lane);
                    f16x8 blb = *((const f16x8*)(base + (size_t)((tb*16+ks)*2+1)*512) + lane);
                    hh0 = MFMA(ah, bha, hh0); hl0 = MFMA(ah, bla, hl0); lh0 = MFMA(al, bha, lh0);
                    hh1 = MFMA(ah, bhb, hh1); hl1 = MFMA(ah, blb, hl1); lh1 = MFMA(al, bhb, lh1);
                }
                f32x4 a0 = hh0 + hl0 + lh0, a1 = hh1 + hl1 + lh1;
                // within a 16-col tile: col = m (noise dim), tile index = n
                const float b2a = b2_sg[ta*16 + m15], b2b = b2_sg[tb*16 + m15];
                #pragma unroll
                for (int rg = 0; rg < 4; ++rg) {
                    float va = (a0[rg] + b2a) * dwv[rg];
                    va += __shfl_xor(va, 1); va += __shfl_xor(va, 2);
                    va += __shfl_xor(va, 4); va += __shfl_xor(va, 8);
                    float vb = (a1[rg] + b2b) * dwv[rg];
                    vb += __shfl_xor(vb, 1); vb += __shfl_xor(vb, 2);
                    vb += __shfl_xor(vb, 4); vb += __shfl_xor(vb, 8);
                    if (m15 == 0) {
                        s_delta[quad*4+rg][ta] = va;
                        s_delta[quad*4+rg][tb] = vb;
                    }
                }
            }
        }
        __syncthreads();

        // ---- phase 5: y update + next x/dW build + out write
        for (int e = tid; e < R*Nn; e += NT) {
            int r = e >> 6, n = e & 63;
            float yv = s_y[r][n] + s_drift[r][n]*0.01f + s_delta[r][n];
            s_y[r][n] = yv;
            out[((size_t)(k+1)*Bb + (r0+r))*Nn + n] = yv;
            _Float16 h = (_Float16)yv;
            s_xhi[r][n] = h; s_xlo[r][n] = (_Float16)(yv - (float)h);
        }
        if (k + 1 < Tt - 1) {
            if (tid < Cc) {
                float u = controls[(size_t)(k+1)*Cc + tid];
                _Float16 h = (_Float16)u, l = (_Float16)(u - (float)h);
                for (int r = 0; r < R; ++r) { s_xhi[r][64+tid] = h; s_xlo[r][64+tid] = l; }
            }
            if (tid < 256) {
                int r = tid >> 4, c = tid & 15;
                s_dw[r][c] = noise[((size_t)(k+1)*Bb + (r0+r))*Mm + c] * 0.1f;
            }
        }
        __syncthreads();
    }
}

extern "C" void kernel_launch(void* const* d_in, const int* in_sizes, int n_in,
                              void* d_out, int out_size, void* d_ws, size_t ws_size,
                              hipStream_t stream) {
    const float* y0       = (const float*)d_in[0];
    const float* controls = (const float*)d_in[1];
    const float* noise    = (const float*)d_in[2];
    const float* W1_mu    = (const float*)d_in[3];
    const float* b1_mu    = (const float*)d_in[4];
    const float* W2_mu    = (const float*)d_in[5];
    const float* b2_mu    = (const float*)d_in[6];
    const float* W1_sg    = (const float*)d_in[7];
    const float* b1_sg    = (const float*)d_in[8];
    const float* W2_sg    = (const float*)d_in[9];
    const float* b2_sg    = (const float*)d_in[10];
    float* out = (float*)d_out;
    _Float16* wsh = (_Float16*)d_ws;

    pack_weights<<<320, 256, 0, stream>>>(W1_mu, W2_mu, W1_sg, W2_sg, wsh);
    nsde_mfma<<<64, NT, 0, stream>>>(y0, controls, noise,
                                     b1_mu, b2_mu, b1_sg, b2_sg,
                                     (const _Float16*)wsh, out);
}

// Round 3
// 3853.804 us; speedup vs baseline: 2.5216x; 2.0590x over previous
//
#include <hip/hip_runtime.h>

// Neural SDE rollout, split-K across blocks, full-chip.
// 32 groups x 32 batch rows; 8 blocks/group, each owns a 64-col H-slice
// (W1[:,slice] and W2[slice,:]) => no activation exchange, only a per-step
// partial-sum exchange via device-scope atomicAdd + release counter.
// Readers use relaxed atomic loads (coherence point) -- NO acquire fences,
// so per-XCD L2 weight caching survives across steps.
// Split-fp16 numerics (hi+lo, 3 MFMA products) as validated in R2.

typedef _Float16 f16x8 __attribute__((ext_vector_type(8)));
typedef float    f32x4 __attribute__((ext_vector_type(4)));

#define MFMA(a,b,c) __builtin_amdgcn_mfma_f32_16x16x32_f16(a,b,c,0,0,0)

#define Bb 1024
#define Tt 128
#define NG 32          // groups
#define GB 8           // blocks per group
#define R32 32         // rows per group
#define NT 512         // threads per block (8 waves)

// packed fragment regions in d_ws (units: halves) -- identical to R2 pack
#define W2SG_OFF 0
#define W2SG_HALVES (64*16*2*512)
#define W2MU_OFF (W2SG_OFF + W2SG_HALVES)
#define W2MU_HALVES (4*16*2*512)
#define W1MU_OFF (W2MU_OFF + W2MU_HALVES)
#define W1_HALVES (32*3*2*512)
#define W1SG_OFF (W1MU_OFF + W1_HALVES)
#define WS_HALVES (W1SG_OFF + W1_HALVES)          // 1,310,720 halves
#define ACC_BYTES_OFF ((size_t)WS_HALVES * 2)     // 2,621,440 B
#define ACC_FLOATS (3 * NG * 2048)                // 3 slots x 32 groups x 32x64
#define CNT_BYTES_OFF (ACC_BYTES_OFF + (size_t)ACC_FLOATS * 4)

__global__ __launch_bounds__(256) void pack_weights(
    const float* __restrict__ W1_mu, const float* __restrict__ W2_mu,
    const float* __restrict__ W1_sg, const float* __restrict__ W2_sg,
    _Float16* __restrict__ wsh)
{
    int gid = blockIdx.x * 256 + threadIdx.x;
    if (gid >= 81920) return;
    const float* src; int ncols, kvalid; size_t dst;
    int id, tile, ks, lane;
    if (gid < 65536) {                 // W2_sg: 64 tiles x 16 ks x 64 lanes
        id = gid; tile = id >> 10; id &= 1023; ks = id >> 6; lane = id & 63;
        src = W2_sg; ncols = 1024; kvalid = 512;
        dst = W2SG_OFF + (size_t)((tile*16 + ks)*2) * 512 + lane*8;
    } else if (gid < 69632) {          // W2_mu: 4 x 16 x 64
        id = gid - 65536; tile = id >> 10; id &= 1023; ks = id >> 6; lane = id & 63;
        src = W2_mu; ncols = 64; kvalid = 512;
        dst = W2MU_OFF + (size_t)((tile*16 + ks)*2) * 512 + lane*8;
    } else if (gid < 75776) {          // W1_mu: 32 tiles x 3 ks x 64
        id = gid - 69632; tile = id / 192; id %= 192; ks = id >> 6; lane = id & 63;
        src = W1_mu; ncols = 512; kvalid = 80;
        dst = W1MU_OFF + (size_t)((tile*3 + ks)*2) * 512 + lane*8;
    } else {                           // W1_sg
        id = gid - 75776; tile = id / 192; id %= 192; ks = id >> 6; lane = id & 63;
        src = W1_sg; ncols = 512; kvalid = 80;
        dst = W1SG_OFF + (size_t)((tile*3 + ks)*2) * 512 + lane*8;
    }
    const int n  = tile*16 + (lane & 15);
    const int kb = ks*32 + ((lane >> 4) << 3);
    f16x8 hi8, lo8;
    #pragma unroll
    for (int jj = 0; jj < 8; ++jj) {
        int k = kb + jj;
        float wv = (k < kvalid) ? src[(size_t)k * ncols + n] : 0.f;
        _Float16 h = (_Float16)wv;
        hi8[jj] = h;
        lo8[jj] = (_Float16)(wv - (float)h);
    }
    *((f16x8*)(wsh + dst))       = hi8;
    *((f16x8*)(wsh + dst + 512)) = lo8;
}

__global__ __launch_bounds__(NT) void nsde_splitk(
    const float* __restrict__ y0, const float* __restrict__ controls,
    const float* __restrict__ noise,
    const float* __restrict__ b1_mu, const float* __restrict__ b2_mu,
    const float* __restrict__ b1_sg, const float* __restrict__ b2_sg,
    const _Float16* __restrict__ wf,
    float* __restrict__ accbuf, unsigned int* __restrict__ cnt,
    float* __restrict__ out)
{
    __shared__ _Float16 s_xhi[R32][104], s_xlo[R32][104];   // x, K=96 (+pad)
    __shared__ _Float16 s_hhi[2][R32][72], s_hlo[2][R32][72]; // h slices (64+pad)
    __shared__ float s_y[2048];     // [r*64+n]
    __shared__ float s_dw[R32][16];
    __shared__ float s_part[2048];  // sg partial (dW-folded)
    __shared__ float s_pmu[2048];   // mu partial (*dt)

    const int tid  = threadIdx.x;
    const int lane = tid & 63, w = tid >> 6;
    const int m15  = lane & 15, quad = lane >> 4;
    const int j    = blockIdx.x & 7;        // K-slice id (round-robin -> XCD)
    const int g    = blockIdx.x >> 3;       // group
    const int r0   = g * R32;

    // ---- per-wave constants
    const int l  = w >> 2;                  // GEMM1 layer: 0=mu 1=sg
    const int ct = w & 3;                   // GEMM1 col-tile within slice
    const int tg = j*4 + ct;                // global W1 H-tile
    const _Float16* w1base = wf + (l ? W1SG_OFF : W1MU_OFF);
    const float bias1 = (l ? b1_sg : b1_mu)[j*64 + ct*16 + m15];
    float b2v[8];
    #pragma unroll
    for (int t = 0; t < 8; ++t)
        b2v[t] = (j == 0) ? b2_sg[(w + t*8)*16 + m15] : 0.f;
    const float b2m = (w < 4 && j == 0) ? b2_mu[w*16 + m15] * 0.01f : 0.f;

    // ---- init
    for (int e = tid; e < R32*24; e += NT) {   // zero K-pad cols 80..103
        int r = e / 24, c = 80 + e % 24;
        s_xhi[r][c] = (_Float16)0.f; s_xlo[r][c] = (_Float16)0.f;
    }
    {
        int c0 = tid*4, r = c0 >> 6, n = c0 & 63;
        float4 yv = *(const float4*)&y0[(size_t)(r0 + r)*64 + n];
        float vv[4] = {yv.x, yv.y, yv.z, yv.w};
        #pragma unroll
        for (int q = 0; q < 4; ++q) {
            s_y[c0+q] = vv[q];
            _Float16 h = (_Float16)vv[q];
            s_xhi[r][n+q] = h; s_xlo[r][n+q] = (_Float16)(vv[q] - (float)h);
        }
        if (((tid & 15) >> 1) == j)
            *(float4*)&out[(size_t)(r0 + r)*64 + n] = yv;
    }
    {
        int r = tid >> 4, c = tid & 15;
        float u = controls[c];
        _Float16 h = (_Float16)u;
        s_xhi[r][64+c] = h; s_xlo[r][64+c] = (_Float16)(u - (float)h);
        s_dw[r][c] = noise[(size_t)(r0 + r)*16 + c] * 0.1f;
    }
    __syncthreads();

    for (int k = 0; k < Tt-1; ++k) {
        // ======== GEMM1: h[l][:, slice] = relu(x @ W1[:, slice] + b1)
        {
            f32x4 a1[2][3];
            #pragma unroll
            for (int mt = 0; mt < 2; ++mt)
                #pragma unroll
                for (int p = 0; p < 3; ++p) a1[mt][p] = (f32x4){0,0,0,0};
            #pragma unroll
            for (int ks = 0; ks < 3; ++ks) {
                const _Float16* bp = w1base + (size_t)((tg*3 + ks)*2)*512 + lane*8;
                f16x8 bh = *(const f16x8*)bp;
                f16x8 bl = *(const f16x8*)(bp + 512);
                #pragma unroll
                for (int mt = 0; mt < 2; ++mt) {
                    f16x8 ah = *(const f16x8*)&s_xhi[mt*16+m15][ks*32 + quad*8];
                    f16x8 al = *(const f16x8*)&s_xlo[mt*16+m15][ks*32 + quad*8];
                    a1[mt][0] = MFMA(ah, bh, a1[mt][0]);
                    a1[mt][1] = MFMA(ah, bl, a1[mt][1]);
                    a1[mt][2] = MFMA(al, bh, a1[mt][2]);
                }
            }
            #pragma unroll
            for (int mt = 0; mt < 2; ++mt) {
                f32x4 s = a1[mt][0] + a1[mt][1] + a1[mt][2];
                #pragma unroll
                for (int rg = 0; rg < 4; ++rg) {
                    int row = mt*16 + quad*4 + rg;
                    float v = fmaxf(s[rg] + bias1, 0.f);
                    _Float16 h = (_Float16)v;
                    s_hhi[l][row][ct*16 + m15] = h;
                    s_hlo[l][row][ct*16 + m15] = (_Float16)(v - (float)h);
                }
            }
        }
        __syncthreads();

        // ======== GEMM2 over this block's K-slice (local k in [0,64))
        float dwv[2][4];
        #pragma unroll
        for (int mt = 0; mt < 2; ++mt)
            #pragma unroll
            for (int rg = 0; rg < 4; ++rg)
                dwv[mt][rg] = s_dw[mt*16 + quad*4 + rg][m15];

        // -- mu partial (waves 0..3): nt = w
        if (w < 4) {
            f16x8 Mh[2][2], Ml[2][2];
            #pragma unroll
            for (int mt = 0; mt < 2; ++mt)
                #pragma unroll
                for (int ksl = 0; ksl < 2; ++ksl) {
                    Mh[mt][ksl] = *(const f16x8*)&s_hhi[0][mt*16+m15][ksl*32 + quad*8];
                    Ml[mt][ksl] = *(const f16x8*)&s_hlo[0][mt*16+m15][ksl*32 + quad*8];
                }
            const _Float16* bp = wf + W2MU_OFF + (size_t)((w*16 + 2*j)*2)*512 + lane*8;
            f16x8 bh0 = *(const f16x8*)(bp);
            f16x8 bl0 = *(const f16x8*)(bp + 512);
            f16x8 bh1 = *(const f16x8*)(bp + 1024);
            f16x8 bl1 = *(const f16x8*)(bp + 1536);
            #pragma unroll
            for (int mt = 0; mt < 2; ++mt) {
                f32x4 hh = {0,0,0,0}, hl = {0,0,0,0}, lh = {0,0,0,0};
                hh = MFMA(Mh[mt][0], bh0, hh); hl = MFMA(Mh[mt][0], bl0, hl); lh = MFMA(Ml[mt][0], bh0, lh);
                hh = MFMA(Mh[mt][1], bh1, hh); hl = MFMA(Mh[mt][1], bl1, hl); lh = MFMA(Ml[mt][1], bh1, lh);
                f32x4 s = hh + hl + lh;
                #pragma unroll
                for (int rg = 0; rg < 4; ++rg) {
                    int row = mt*16 + quad*4 + rg;
                    s_pmu[row*64 + w*16 + m15] = s[rg]*0.01f + b2m;
                }
            }
        }

        // -- sg partial: A frags (h_sg slice), then 8 n-tiles per wave
        f16x8 Ah[2][2], Al[2][2];
        #pragma unroll
        for (int mt = 0; mt < 2; ++mt)
            #pragma unroll
            for (int ksl = 0; ksl < 2; ++ksl) {
                Ah[mt][ksl] = *(const f16x8*)&s_hhi[1][mt*16+m15][ksl*32 + quad*8];
                Al[mt][ksl] = *(const f16x8*)&s_hlo[1][mt*16+m15][ksl*32 + quad*8];
            }
        #pragma unroll 2
        for (int t = 0; t < 8; ++t) {
            const int nt = w + t*8;
            const _Float16* bp = wf + W2SG_OFF + (size_t)((nt*16 + 2*j)*2)*512 + lane*8;
            f16x8 bh0 = *(const f16x8*)(bp);
            f16x8 bl0 = *(const f16x8*)(bp + 512);
            f16x8 bh1 = *(const f16x8*)(bp + 1024);
            f16x8 bl1 = *(const f16x8*)(bp + 1536);
            #pragma unroll
            for (int mt = 0; mt < 2; ++mt) {
                f32x4 hh = {0,0,0,0}, hl = {0,0,0,0}, lh = {0,0,0,0};
                hh = MFMA(Ah[mt][0], bh0, hh); hl = MFMA(Ah[mt][0], bl0, hl); lh = MFMA(Al[mt][0], bh0, lh);
                hh = MFMA(Ah[mt][1], bh1, hh); hl = MFMA(Ah[mt][1], bl1, hl); lh = MFMA(Al[mt][1], bh1, lh);
                f32x4 s = hh + hl + lh;
                #pragma unroll
                for (int rg = 0; rg < 4; ++rg) {
                    float v = (s[rg] + b2v[t]) * dwv[mt][rg];
                    v += __shfl_xor(v, 1); v += __shfl_xor(v, 2);
                    v += __shfl_xor(v, 4); v += __shfl_xor(v, 8);
                    if (m15 == 0) s_part[(mt*16 + quad*4 + rg)*64 + nt] = v;
                }
            }
        }
        __syncthreads();

        // ======== exchange: atomicAdd partials into slot k%3
        const int slot = k % 3;
        float* ab = accbuf + ((size_t)slot*NG + g)*2048;
        {
            int c0 = tid*4;
            #pragma unroll
            for (int q = 0; q < 4; ++q) {
                float v = s_part[c0+q] + s_pmu[c0+q];
                __hip_atomic_fetch_add(&ab[c0+q], v, __ATOMIC_RELAXED,
                                       __HIP_MEMORY_SCOPE_AGENT);
            }
        }
        __syncthreads();   // all adds drained (waitcnt before barrier)
        if (tid == 0) {
            __hip_atomic_fetch_add(&cnt[g], 1u, __ATOMIC_RELEASE,
                                   __HIP_MEMORY_SCOPE_AGENT);
            while (__hip_atomic_load(&cnt[g], __ATOMIC_RELAXED,
                                     __HIP_MEMORY_SCOPE_AGENT) < 8u*(unsigned)(k+1))
                __builtin_amdgcn_s_sleep(2);
        }
        __syncthreads();

        // ======== read sum (coherence-point loads), y update, next x/dW
        {
            int c0 = tid*4, r = c0 >> 6, n = c0 & 63;
            float yv[4];
            #pragma unroll
            for (int q = 0; q < 4; ++q) {
                float sum = __hip_atomic_load(&ab[c0+q], __ATOMIC_RELAXED,
                                              __HIP_MEMORY_SCOPE_AGENT);
                float y = s_y[c0+q] + sum;
                s_y[c0+q] = y; yv[q] = y;
                _Float16 h = (_Float16)y;
                s_xhi[r][n+q] = h; s_xlo[r][n+q] = (_Float16)(y - (float)h);
            }
            if (((tid & 15) >> 1) == j) {
                float4 o = {yv[0], yv[1], yv[2], yv[3]};
                *(float4*)&out[((size_t)(k+1)*Bb + r0 + r)*64 + n] = o;
                if (k >= 1) {   // zero slot (k-1)%3 (safe: 3-slot rotation)
                    float* zb = accbuf + ((size_t)((k-1)%3)*NG + g)*2048;
                    #pragma unroll
                    for (int q = 0; q < 4; ++q)
                        __hip_atomic_store(&zb[c0+q], 0.f, __ATOMIC_RELAXED,
                                           __HIP_MEMORY_SCOPE_AGENT);
                }
            }
        }
        if (k < Tt-2) {
            int r = tid >> 4, c = tid & 15;
            float u = controls[(size_t)(k+1)*16 + c];
            _Float16 h = (_Float16)u;
            s_xhi[r][64+c] = h; s_xlo[r][64+c] = (_Float16)(u - (float)h);
            s_dw[r][c] = noise[((size_t)(k+1)*Bb + r0 + r)*16 + c] * 0.1f;
        }
        __syncthreads();
    }
}

extern "C" void kernel_launch(void* const* d_in, const int* in_sizes, int n_in,
                              void* d_out, int out_size, void* d_ws, size_t ws_size,
                              hipStream_t stream) {
    const float* y0       = (const float*)d_in[0];
    const float* controls = (const float*)d_in[1];
    const float* noise    = (const float*)d_in[2];
    const float* W1_mu    = (const float*)d_in[3];
    const float* b1_mu    = (const float*)d_in[4];
    const float* W2_mu    = (const float*)d_in[5];
    const float* b2_mu    = (const float*)d_in[6];
    const float* W1_sg    = (const float*)d_in[7];
    const float* b1_sg    = (const float*)d_in[8];
    const float* W2_sg    = (const float*)d_in[9];
    const float* b2_sg    = (const float*)d_in[10];
    float* out = (float*)d_out;
    _Float16* wsh = (_Float16*)d_ws;
    float* accbuf = (float*)((char*)d_ws + ACC_BYTES_OFF);
    unsigned int* cnt = (unsigned int*)((char*)d_ws + CNT_BYTES_OFF);

    // zero the accumulator slots + counters (ws is poisoned 0xAA each call)
    hipMemsetAsync((char*)d_ws + ACC_BYTES_OFF, 0,
                   (size_t)ACC_FLOATS*4 + NG*4, stream);
    pack_weights<<<320, 256, 0, stream>>>(W1_mu, W2_mu, W1_sg, W2_sg, wsh);
    nsde_splitk<<<NG*GB, NT, 0, stream>>>(y0, controls, noise,
                                          b1_mu, b2_mu, b1_sg, b2_sg,
                                          (const _Float16*)wsh,
                                          accbuf, cnt, out);
}

// Round 4
// 2293.843 us; speedup vs baseline: 4.2364x; 1.6801x over previous
//
#include <hip/hip_runtime.h>

// Neural SDE rollout, split-K across blocks, full-chip, 2 blocks/CU.
// 64 groups x 16 batch rows; 8 blocks/group, each owns a 64-col H-slice
// (W1[:,slice], W2[slice,:]). Per-step partial-sum exchange via device-scope
// atomicAdd + release counter (validated R3, absmax 2.0). Relaxed atomic
// loads as coherence-point reads -- no acquire fences, so per-XCD L2 weight
// caching survives across steps.
// Key change vs R3: 16-row groups -> 512 blocks x 512 thr, LDS ~29 KB,
// VGPR<=128 => 2 co-resident blocks/CU (4 waves/SIMD) whose barrier/spin
// schedules are decoupled -> latency of one block hidden by the other.

typedef _Float16 f16x8 __attribute__((ext_vector_type(8)));
typedef float    f32x4 __attribute__((ext_vector_type(4)));

#define MFMA(a,b,c) __builtin_amdgcn_mfma_f32_16x16x32_f16(a,b,c,0,0,0)

#define Bb 1024
#define Tt 128
#define NG 64          // groups
#define GB 8           // blocks per group (split-K over H=512 -> 64 cols each)
#define Rr 16          // rows per group (one MFMA M-tile)
#define NT 512         // threads per block (8 waves)

// packed fragment regions in d_ws (units: halves) -- identical pack to R3
#define W2SG_OFF 0
#define W2SG_HALVES (64*16*2*512)
#define W2MU_OFF (W2SG_OFF + W2SG_HALVES)
#define W2MU_HALVES (4*16*2*512)
#define W1MU_OFF (W2MU_OFF + W2MU_HALVES)
#define W1_HALVES (32*3*2*512)
#define W1SG_OFF (W1MU_OFF + W1_HALVES)
#define WS_HALVES (W1SG_OFF + W1_HALVES)
#define ACC_BYTES_OFF ((size_t)WS_HALVES * 2)
#define ACC_FLOATS (3 * NG * 1024)        // 3 slots x 64 groups x 16x64
#define CNT_BYTES_OFF (ACC_BYTES_OFF + (size_t)ACC_FLOATS * 4)
#define CNT_STRIDE 16                     // pad counters to 64 B

__global__ __launch_bounds__(256) void pack_weights(
    const float* __restrict__ W1_mu, const float* __restrict__ W2_mu,
    const float* __restrict__ W1_sg, const float* __restrict__ W2_sg,
    _Float16* __restrict__ wsh)
{
    int gid = blockIdx.x * 256 + threadIdx.x;
    if (gid >= 81920) return;
    const float* src; int ncols, kvalid; size_t dst;
    int id, tile, ks, lane;
    if (gid < 65536) {                 // W2_sg: 64 tiles x 16 ks x 64 lanes
        id = gid; tile = id >> 10; id &= 1023; ks = id >> 6; lane = id & 63;
        src = W2_sg; ncols = 1024; kvalid = 512;
        dst = W2SG_OFF + (size_t)((tile*16 + ks)*2) * 512 + lane*8;
    } else if (gid < 69632) {          // W2_mu: 4 x 16 x 64
        id = gid - 65536; tile = id >> 10; id &= 1023; ks = id >> 6; lane = id & 63;
        src = W2_mu; ncols = 64; kvalid = 512;
        dst = W2MU_OFF + (size_t)((tile*16 + ks)*2) * 512 + lane*8;
    } else if (gid < 75776) {          // W1_mu: 32 tiles x 3 ks x 64
        id = gid - 69632; tile = id / 192; id %= 192; ks = id >> 6; lane = id & 63;
        src = W1_mu; ncols = 512; kvalid = 80;
        dst = W1MU_OFF + (size_t)((tile*3 + ks)*2) * 512 + lane*8;
    } else {                           // W1_sg
        id = gid - 75776; tile = id / 192; id %= 192; ks = id >> 6; lane = id & 63;
        src = W1_sg; ncols = 512; kvalid = 80;
        dst = W1SG_OFF + (size_t)((tile*3 + ks)*2) * 512 + lane*8;
    }
    const int n  = tile*16 + (lane & 15);
    const int kb = ks*32 + ((lane >> 4) << 3);
    f16x8 hi8, lo8;
    #pragma unroll
    for (int jj = 0; jj < 8; ++jj) {
        int k = kb + jj;
        float wv = (k < kvalid) ? src[(size_t)k * ncols + n] : 0.f;
        _Float16 h = (_Float16)wv;
        hi8[jj] = h;
        lo8[jj] = (_Float16)(wv - (float)h);
    }
    *((f16x8*)(wsh + dst))       = hi8;
    *((f16x8*)(wsh + dst + 512)) = lo8;
}

__global__ __launch_bounds__(NT, 4) void nsde_splitk(
    const float* __restrict__ y0, const float* __restrict__ controls,
    const float* __restrict__ noise,
    const float* __restrict__ b1_mu, const float* __restrict__ b2_mu,
    const float* __restrict__ b1_sg, const float* __restrict__ b2_sg,
    const _Float16* __restrict__ wf,
    float* __restrict__ accbuf, unsigned int* __restrict__ cnt,
    float* __restrict__ out)
{
    __shared__ _Float16 s_xhi[Rr][104], s_xlo[Rr][104];     // x, K=96 (+pad)
    __shared__ _Float16 s_hhi[2][Rr][72], s_hlo[2][Rr][72]; // h slices (64+pad)
    __shared__ float s_y[Rr*64];     // [r*64+n]
    __shared__ float s_dw[Rr][16];
    __shared__ float s_part[Rr*64];  // sg partial (dW-folded)
    __shared__ float s_pmu[Rr*64];   // mu partial (*dt)

    const int tid  = threadIdx.x;
    const int lane = tid & 63, w = tid >> 6;
    const int m15  = lane & 15, quad = lane >> 4;
    const int j    = blockIdx.x & 7;        // K-slice id
    const int g    = blockIdx.x >> 3;       // group
    const int r0   = g * Rr;

    // per-wave constants
    const int l  = w >> 2;                  // GEMM1 layer: 0=mu 1=sg
    const int ct = w & 3;                   // GEMM1 col-tile within slice
    const int tg = j*4 + ct;                // global W1 H-tile
    const _Float16* w1base = wf + (l ? W1SG_OFF : W1MU_OFF);
    const float bias1 = (l ? b1_sg : b1_mu)[j*64 + ct*16 + m15];
    float b2v[8];
    #pragma unroll
    for (int t = 0; t < 8; ++t)
        b2v[t] = (j == 0) ? b2_sg[(w + t*8)*16 + m15] : 0.f;
    const float b2m = (w < 4 && j == 0) ? b2_mu[w*16 + m15] * 0.01f : 0.f;

    // ---- init
    for (int e = tid; e < Rr*24; e += NT) {   // zero x K-pad cols 80..103
        int r = e / 24, c = 80 + e % 24;
        s_xhi[r][c] = (_Float16)0.f; s_xlo[r][c] = (_Float16)0.f;
    }
    if (tid < 256) {
        int e0 = tid*4, r = e0 >> 6, n = e0 & 63;
        float4 yv = *(const float4*)&y0[(size_t)(r0 + r)*64 + n];
        float vv[4] = {yv.x, yv.y, yv.z, yv.w};
        #pragma unroll
        for (int q = 0; q < 4; ++q) {
            s_y[e0+q] = vv[q];
            _Float16 h = (_Float16)vv[q];
            s_xhi[r][n+q] = h; s_xlo[r][n+q] = (_Float16)(vv[q] - (float)h);
        }
        if ((tid >> 5) == j)
            *(float4*)&out[(size_t)(r0 + r)*64 + n] = yv;
        int rr2 = tid >> 4, cc2 = tid & 15;
        float u = controls[cc2];
        _Float16 h = (_Float16)u;
        s_xhi[rr2][64+cc2] = h; s_xlo[rr2][64+cc2] = (_Float16)(u - (float)h);
        s_dw[rr2][cc2] = noise[(size_t)(r0 + rr2)*16 + cc2] * 0.1f;
    }
    __syncthreads();

    for (int k = 0; k < Tt-1; ++k) {
        // ======== GEMM1: one 16-col tile per wave, both layers in parallel
        {
            f32x4 a0 = {0,0,0,0}, a1 = {0,0,0,0}, a2 = {0,0,0,0};
            #pragma unroll
            for (int ks = 0; ks < 3; ++ks) {
                const _Float16* bp = w1base + (size_t)((tg*3 + ks)*2)*512 + lane*8;
                f16x8 bh = *(const f16x8*)bp;
                f16x8 bl = *(const f16x8*)(bp + 512);
                f16x8 ah = *(const f16x8*)&s_xhi[m15][ks*32 + quad*8];
                f16x8 al = *(const f16x8*)&s_xlo[m15][ks*32 + quad*8];
                a0 = MFMA(ah, bh, a0);
                a1 = MFMA(ah, bl, a1);
                a2 = MFMA(al, bh, a2);
            }
            f32x4 s = a0 + a1 + a2;
            #pragma unroll
            for (int rg = 0; rg < 4; ++rg) {
                int row = quad*4 + rg;
                float v = fmaxf(s[rg] + bias1, 0.f);
                _Float16 h = (_Float16)v;
                s_hhi[l][row][ct*16 + m15] = h;
                s_hlo[l][row][ct*16 + m15] = (_Float16)(v - (float)h);
            }
        }
        __syncthreads();

        // ======== GEMM2 over this block's K-slice (local k in [0,64))
        float dwv[4];
        #pragma unroll
        for (int rg = 0; rg < 4; ++rg)
            dwv[rg] = s_dw[quad*4 + rg][m15];

        // -- mu partial (waves 0..3 take n-tile w)
        if (w < 4) {
            f16x8 Mh0 = *(const f16x8*)&s_hhi[0][m15][quad*8];
            f16x8 Ml0 = *(const f16x8*)&s_hlo[0][m15][quad*8];
            f16x8 Mh1 = *(const f16x8*)&s_hhi[0][m15][32 + quad*8];
            f16x8 Ml1 = *(const f16x8*)&s_hlo[0][m15][32 + quad*8];
            const _Float16* bp = wf + W2MU_OFF + (size_t)((w*16 + 2*j)*2)*512 + lane*8;
            f16x8 bh0 = *(const f16x8*)(bp);
            f16x8 bl0 = *(const f16x8*)(bp + 512);
            f16x8 bh1 = *(const f16x8*)(bp + 1024);
            f16x8 bl1 = *(const f16x8*)(bp + 1536);
            f32x4 hh = {0,0,0,0}, hl = {0,0,0,0}, lh = {0,0,0,0};
            hh = MFMA(Mh0, bh0, hh); hl = MFMA(Mh0, bl0, hl); lh = MFMA(Ml0, bh0, lh);
            hh = MFMA(Mh1, bh1, hh); hl = MFMA(Mh1, bl1, hl); lh = MFMA(Ml1, bh1, lh);
            f32x4 s = hh + hl + lh;
            #pragma unroll
            for (int rg = 0; rg < 4; ++rg)
                s_pmu[(quad*4 + rg)*64 + w*16 + m15] = s[rg]*0.01f + b2m;
        }

        // -- sg partials: 8 n-tiles per wave
        f16x8 Ah0 = *(const f16x8*)&s_hhi[1][m15][quad*8];
        f16x8 Al0 = *(const f16x8*)&s_hlo[1][m15][quad*8];
        f16x8 Ah1 = *(const f16x8*)&s_hhi[1][m15][32 + quad*8];
        f16x8 Al1 = *(const f16x8*)&s_hlo[1][m15][32 + quad*8];
        #pragma unroll 2
        for (int t = 0; t < 8; ++t) {
            const int nt = w + t*8;
            const _Float16* bp = wf + W2SG_OFF + (size_t)((nt*16 + 2*j)*2)*512 + lane*8;
            f16x8 bh0 = *(const f16x8*)(bp);
            f16x8 bl0 = *(const f16x8*)(bp + 512);
            f16x8 bh1 = *(const f16x8*)(bp + 1024);
            f16x8 bl1 = *(const f16x8*)(bp + 1536);
            f32x4 hh = {0,0,0,0}, hl = {0,0,0,0}, lh = {0,0,0,0};
            hh = MFMA(Ah0, bh0, hh); hl = MFMA(Ah0, bl0, hl); lh = MFMA(Al0, bh0, lh);
            hh = MFMA(Ah1, bh1, hh); hl = MFMA(Ah1, bl1, hl); lh = MFMA(Al1, bh1, lh);
            f32x4 s = hh + hl + lh;
            #pragma unroll
            for (int rg = 0; rg < 4; ++rg) {
                float v = (s[rg] + b2v[t]) * dwv[rg];
                v += __shfl_xor(v, 1); v += __shfl_xor(v, 2);
                v += __shfl_xor(v, 4); v += __shfl_xor(v, 8);
                if (m15 == 0) s_part[(quad*4 + rg)*64 + nt] = v;
            }
        }
        __syncthreads();

        // ======== exchange: atomicAdd partials into slot k%3
        const int slot = k % 3;
        float* ab = accbuf + ((size_t)slot*NG + g)*1024;
        const int e0 = tid*2;
        {
            float v0 = s_part[e0]   + s_pmu[e0];
            float v1 = s_part[e0+1] + s_pmu[e0+1];
            __hip_atomic_fetch_add(&ab[e0],   v0, __ATOMIC_RELAXED,
                                   __HIP_MEMORY_SCOPE_AGENT);
            __hip_atomic_fetch_add(&ab[e0+1], v1, __ATOMIC_RELAXED,
                                   __HIP_MEMORY_SCOPE_AGENT);
        }
        __syncthreads();   // drains vmcnt: all adds complete
        if (tid == 0) {
            __hip_atomic_fetch_add(&cnt[g*CNT_STRIDE], 1u, __ATOMIC_RELEASE,
                                   __HIP_MEMORY_SCOPE_AGENT);
            while (__hip_atomic_load(&cnt[g*CNT_STRIDE], __ATOMIC_RELAXED,
                                     __HIP_MEMORY_SCOPE_AGENT) < (unsigned)GB*(k+1))
                __builtin_amdgcn_s_sleep(2);
        }
        __syncthreads();

        // ======== read sum, y update, out write, next x/dW build
        {
            const int r = e0 >> 6, n = e0 & 63;
            float sum0 = __hip_atomic_load(&ab[e0], __ATOMIC_RELAXED,
                                           __HIP_MEMORY_SCOPE_AGENT);
            float sum1 = __hip_atomic_load(&ab[e0+1], __ATOMIC_RELAXED,
                                           __HIP_MEMORY_SCOPE_AGENT);
            float ya = s_y[e0]   + sum0;
            float yb = s_y[e0+1] + sum1;
            s_y[e0] = ya; s_y[e0+1] = yb;
            _Float16 ha = (_Float16)ya, hb = (_Float16)yb;
            s_xhi[r][n] = ha;   s_xlo[r][n]   = (_Float16)(ya - (float)ha);
            s_xhi[r][n+1] = hb; s_xlo[r][n+1] = (_Float16)(yb - (float)hb);
            if ((tid >> 6) == j) {   // wave j writes this block's 128-elem chunk
                float2 o = {ya, yb};
                *(float2*)&out[((size_t)(k+1)*Bb + r0 + r)*64 + n] = o;
                if (k >= 1) {        // zero slot (k-1)%3 (3-slot rotation safe)
                    float* zb = accbuf + ((size_t)((k-1)%3)*NG + g)*1024;
                    __hip_atomic_store(&zb[e0],   0.f, __ATOMIC_RELAXED,
                                       __HIP_MEMORY_SCOPE_AGENT);
                    __hip_atomic_store(&zb[e0+1], 0.f, __ATOMIC_RELAXED,
                                       __HIP_MEMORY_SCOPE_AGENT);
                }
            }
        }
        if (k < Tt-2 && tid < 256) {
            int r = tid >> 4, c = tid & 15;
            float u = controls[(size_t)(k+1)*16 + c];
            _Float16 h = (_Float16)u;
            s_xhi[r][64+c] = h; s_xlo[r][64+c] = (_Float16)(u - (float)h);
            s_dw[r][c] = noise[((size_t)(k+1)*Bb + r0 + r)*16 + c] * 0.1f;
        }
        __syncthreads();
    }
}

extern "C" void kernel_launch(void* const* d_in, const int* in_sizes, int n_in,
                              void* d_out, int out_size, void* d_ws, size_t ws_size,
                              hipStream_t stream) {
    const float* y0       = (const float*)d_in[0];
    const float* controls = (const float*)d_in[1];
    const float* noise    = (const float*)d_in[2];
    const float* W1_mu    = (const float*)d_in[3];
    const float* b1_mu    = (const float*)d_in[4];
    const float* W2_mu    = (const float*)d_in[5];
    const float* b2_mu    = (const float*)d_in[6];
    const float* W1_sg    = (const float*)d_in[7];
    const float* b1_sg    = (const float*)d_in[8];
    const float* W2_sg    = (const float*)d_in[9];
    const float* b2_sg    = (const float*)d_in[10];
    float* out = (float*)d_out;
    _Float16* wsh = (_Float16*)d_ws;
    float* accbuf = (float*)((char*)d_ws + ACC_BYTES_OFF);
    unsigned int* cnt = (unsigned int*)((char*)d_ws + CNT_BYTES_OFF);

    // zero accumulator slots + padded counters (ws is poisoned 0xAA each call)
    hipMemsetAsync((char*)d_ws + ACC_BYTES_OFF, 0,
                   (size_t)ACC_FLOATS*4 + (size_t)NG*CNT_STRIDE*4, stream);
    pack_weights<<<320, 256, 0, stream>>>(W1_mu, W2_mu, W1_sg, W2_sg, wsh);
    nsde_splitk<<<NG*GB, NT, 0, stream>>>(y0, controls, noise,
                                          b1_mu, b2_mu, b1_sg, b2_sg,
                                          (const _Float16*)wsh,
                                          accbuf, cnt, out);
}